// Round 5
// baseline (925.842 us; speedup 1.0000x reference)
//
#include <hip/hip_runtime.h>
#include <hip/hip_cooperative_groups.h>

namespace cg = cooperative_groups;

// HubnormTripletLoss, N=8192.
// P = Sinkhorn(exp(-(1-s)/lamb), 5 iters) == P0 * R[i] * C[j]  (diagonal scaling).
// fp8-e4m3 quantized P0 ("Q") is ~92% exact zeros -> packed CSR (col|fp8<<16),
// CAP=1024/row (nnz ~682+-25).
// R4 post-mortem: per-dispatch cost ~25-35us dominates ALL rounds
// (R3: 754 = 346 pass0 + 11 dispatches x ~37us; R1: 486 = 16 x ~30us).
// => ONE cooperative kernel, 256 blocks x 1024 thr (1 block/CU, co-resident),
// 11 grid.sync()s instead of 15 kernel boundaries. Row steps fused into the
// col-step scatter (entries re-read from L1). Block b owns rows/cols 32b..32b+31.
//   phase A: quantize, CSR, R1=1/rowsum, qdiag           (sims 256MB NT read)
//   phase B x5: [rowstep: R=1/(Q.C) if it>0] + LDS scatter Q^T.R -> part[b]
//               -> sync -> colred (32 cols/block): C=1/sum part
//   phase C: loss over nonzeros; zero-class closed form:
//          sum_k relu(.2-d_k)*(16382+2*[Q_kk!=0]) - per-nz corrections.
// Fallback 1 (coop launch error): R4's multi-kernel sparse path (615us, proven).
// Fallback 2 (tiny ws): dense recompute-from-sims path (slow, safe).

#define NN 8192u
#define CAP 1024u
#define MARGIN 0.2f
#define KF (1.4426950408889634f / 0.012f)  // log2(e)/lamb

typedef float f32x4 __attribute__((ext_vector_type(4)));

__device__ __forceinline__ float wave_sum(float v) {
#pragma unroll
  for (int off = 32; off; off >>= 1) v += __shfl_down(v, off, 64);
  return v;
}
__device__ __forceinline__ float cvt8(uint b) {
  return __builtin_amdgcn_cvt_f32_fp8((int)b, 0);
}

// ========================= COOPERATIVE SINGLE KERNEL =========================

__global__ __launch_bounds__(1024, 4) void k_coop(
    const float* __restrict__ sims, uint* __restrict__ rent,
    uint* __restrict__ nnzg, float* __restrict__ Rg, float* __restrict__ Cg,
    float* __restrict__ qdiag, float* __restrict__ dvec,
    float* __restrict__ part, float* __restrict__ out) {
  __shared__ float Cp[NN];  // 32 KB col-accumulator
  __shared__ float redf[4][4];
  __shared__ uint redc[4][4];
  __shared__ float csum[32];
  __shared__ float cterm[32];
  __shared__ float redw[16];
  cg::grid_group gridg = cg::this_grid();

  const uint b = blockIdx.x, t = threadIdx.x;
  const uint row0 = b * 32u;
  if (b == 0u && t == 0u) *out = 0.f;  // d_out poisoned 0xAA each call

  // ---- phase A: quantize + packed CSR + R1 = 1/rowsum -----------------------
  {
    const uint g = t >> 8, tg = t & 255u;  // 4 groups of 256, 8 rows each
    const uint lane = tg & 63u, wid = tg >> 6;
    for (uint rr = 0; rr < 8u; ++rr) {
      const uint row = row0 + g * 8u + rr;
      uint pk[8];  // static-indexed: stays in VGPRs
      float acc = 0.f;
      uint ct = 0u;
#pragma unroll
      for (uint ch = 0; ch < 8u; ++ch) {
        const uint col0 = ch * 1024u + tg * 4u;
        // nontemporal: sims read exactly once; keep CSR resident in caches
        const f32x4 s = __builtin_nontemporal_load(
            (const f32x4*)(sims + (size_t)row * NN + col0));
        int p = 0;
        p = __builtin_amdgcn_cvt_pk_fp8_f32(exp2f((s[0] - 1.f) * KF),
                                            exp2f((s[1] - 1.f) * KF), p, false);
        p = __builtin_amdgcn_cvt_pk_fp8_f32(exp2f((s[2] - 1.f) * KF),
                                            exp2f((s[3] - 1.f) * KF), p, true);
        const uint up = (uint)p;
        pk[ch] = up;
        auto lo = __builtin_amdgcn_cvt_pk_f32_fp8(p, false);
        auto hi = __builtin_amdgcn_cvt_pk_f32_fp8(p, true);
        acc += (lo[0] + lo[1]) + (hi[0] + hi[1]);  // sum QUANTIZED values
        ct += (uint)((up & 0xFFu) != 0u) + (uint)(((up >> 8) & 0xFFu) != 0u) +
              (uint)(((up >> 16) & 0xFFu) != 0u) + (uint)((up >> 24) != 0u);
        if (row - col0 < 4u)  // this thread's quad holds the diagonal
          qdiag[row] = cvt8((up >> ((row - col0) * 8u)) & 0xFFu);
      }
      // group-wide exclusive offsets: wave scan + cross-wave bases
      uint inc = ct;
#pragma unroll
      for (uint off = 1; off < 64u; off <<= 1) {
        const uint nv = __shfl_up(inc, off, 64);
        if (lane >= off) inc += nv;
      }
      const float wacc = wave_sum(acc);
      if (lane == 63u) redc[g][wid] = inc;
      if (lane == 0u) redf[g][wid] = wacc;
      __syncthreads();
      uint wbase = 0u;
      for (uint w2 = 0; w2 < wid; ++w2) wbase += redc[g][w2];
      if (tg == 0u) {
        nnzg[row] = min(redc[g][0] + redc[g][1] + redc[g][2] + redc[g][3], CAP);
        Rg[row] = 1.f / (redf[g][0] + redf[g][1] + redf[g][2] + redf[g][3]);
      }
      uint ofs = wbase + inc - ct;
      const size_t rb = (size_t)row * CAP;
#pragma unroll
      for (uint ch = 0; ch < 8u; ++ch) {
        const uint up = pk[ch];
        const uint col0 = ch * 1024u + tg * 4u;
#pragma unroll
        for (uint e = 0; e < 4u; ++e) {
          const uint bb = (up >> (8u * e)) & 0xFFu;
          if (bb) {
            if (ofs < CAP)  // graceful drop (statistically never)
              rent[rb + ofs] = (col0 + e) | (bb << 16);
            ++ofs;
          }
        }
      }
      __syncthreads();  // protect redc/redf reuse next round
    }
  }
  gridg.sync();

  // ---- phase B: 5 col steps, row steps fused (it>0) -------------------------
  const uint w = t >> 6, lane = t & 63u;  // 16 waves, 2 rows each
  for (int itx = 0; itx < 5; ++itx) {
    for (uint j = t; j < NN; j += 1024u) Cp[j] = 0.f;
    __syncthreads();
#pragma unroll
    for (uint rr = 0; rr < 2u; ++rr) {
      const uint row = row0 + w * 2u + rr;
      const uint n = nnzg[row];
      const size_t base = (size_t)row * CAP;
      float Rr;
      if (itx == 0) {
        Rr = Rg[row];
      } else {
        // fused row step: R[row] = 1/(Q_row . C)
        float a = 0.f;
        for (uint k = lane; k < n; k += 64u) {
          const uint e = rent[base + k];
          a += cvt8(e >> 16) * Cg[e & 0xFFFFu];
        }
        a = wave_sum(a);
        Rr = 1.f / __shfl(a, 0, 64);
        if (lane == 0u) Rg[row] = Rr;
      }
      // scatter Q_row * Rr into the block's column accumulator (L1-hot reread)
      for (uint k = lane; k < n; k += 64u) {
        const uint e = rent[base + k];
        atomicAdd(&Cp[e & 0xFFFFu], cvt8(e >> 16) * Rr);
      }
    }
    __syncthreads();
    {
      float* po = part + (size_t)b * NN;
      for (uint j4 = t * 4u; j4 < NN; j4 += 4096u)
        *(f32x4*)(po + j4) = *(const f32x4*)(Cp + j4);
    }
    gridg.sync();
    // col reduce: this block owns cols b*32..b*32+31; 32 slices of 8 partials
    {
      const uint colL = t & 31u, q = t >> 5;
      const uint col = b * 32u + colL;
      float s = 0.f;
      const uint r0 = q * 8u;
#pragma unroll
      for (uint r = r0; r < r0 + 8u; ++r) s += part[(size_t)r * NN + col];
      if (t < 32u) csum[t] = 0.f;
      __syncthreads();
      atomicAdd(&csum[colL], s);
      __syncthreads();
      if (t < 32u) {
        const float cv = 1.f / csum[t];
        Cg[col] = cv;
        if (itx == 4) {
          const float qd = qdiag[col];
          const float d = qd * Rg[col] * cv;
          dvec[col] = d;
          // zero-class closed form per index: (8191+[Qjj!=0]) col-anchor
          // + (8191+[Qii!=0]) row-anchor
          cterm[t] =
              fmaxf(MARGIN - d, 0.f) * (16382.f + (qd != 0.f ? 2.f : 0.f));
        }
      }
      if (itx == 4) {
        __syncthreads();
        if (t == 0u) {
          float tt = 0.f;
#pragma unroll
          for (int k2 = 0; k2 < 32; ++k2) tt += cterm[k2];
          atomicAdd(out, tt);
        }
      }
    }
    gridg.sync();
  }

  // ---- phase C: loss over nonzeros (+ zero-class corrections) ---------------
  {
    float acc = 0.f;
#pragma unroll
    for (uint rr = 0; rr < 2u; ++rr) {
      const uint row = row0 + w * 2u + rr;
      const uint n = nnzg[row];
      const float Rr = Rg[row];  // wave-uniform -> scalar
      const float dr = dvec[row];
      const size_t base = (size_t)row * CAP;
      for (uint k = lane; k < n; k += 64u) {
        const uint e = rent[base + k];
        const uint j = e & 0xFFFFu;
        const float dj = dvec[j];
        acc -= fmaxf(MARGIN - dj, 0.f);  // col-anchor zero-class correction
        if (j != row) {
          const float P = cvt8(e >> 16) * Rr * Cg[j];
          acc += fmaxf(P - dj + MARGIN, 0.f) + fmaxf(P - dr + MARGIN, 0.f);
        }
      }
      if (lane == 0u) acc -= (float)n * fmaxf(MARGIN - dr, 0.f);  // row-anchor
    }
    acc = wave_sum(acc);
    if (lane == 0u) redw[w] = acc;
    __syncthreads();
    if (t == 0u) {
      float s = 0.f;
#pragma unroll
      for (int k2 = 0; k2 < 16; ++k2) s += redw[k2];
      atomicAdd(out, s);
    }
  }
}

// ================= FALLBACK 1: R4 multi-kernel sparse path ===================

__global__ __launch_bounds__(256) void k_pass0s(
    const float* __restrict__ sims, uint* __restrict__ rent,
    uint* __restrict__ nnz, float* __restrict__ R, float* __restrict__ qdiag,
    float* __restrict__ out) {
  __shared__ float redf[4];
  __shared__ uint redc[4];
  const uint row = blockIdx.x, t = threadIdx.x;
  const uint lane = t & 63u, wid = t >> 6;
  if (row == 0u && t == 0u) *out = 0.f;
  uint pk[8];
  float acc = 0.f;
  uint ct = 0u;
#pragma unroll
  for (uint ch = 0; ch < 8u; ++ch) {
    const uint col0 = ch * 1024u + t * 4u;
    const f32x4 s = __builtin_nontemporal_load(
        (const f32x4*)(sims + (size_t)row * NN + col0));
    int p = 0;
    p = __builtin_amdgcn_cvt_pk_fp8_f32(exp2f((s[0] - 1.f) * KF),
                                        exp2f((s[1] - 1.f) * KF), p, false);
    p = __builtin_amdgcn_cvt_pk_fp8_f32(exp2f((s[2] - 1.f) * KF),
                                        exp2f((s[3] - 1.f) * KF), p, true);
    const uint up = (uint)p;
    pk[ch] = up;
    auto lo = __builtin_amdgcn_cvt_pk_f32_fp8(p, false);
    auto hi = __builtin_amdgcn_cvt_pk_f32_fp8(p, true);
    acc += (lo[0] + lo[1]) + (hi[0] + hi[1]);
    ct += (uint)((up & 0xFFu) != 0u) + (uint)(((up >> 8) & 0xFFu) != 0u) +
          (uint)(((up >> 16) & 0xFFu) != 0u) + (uint)((up >> 24) != 0u);
    if (row - col0 < 4u)
      qdiag[row] = cvt8((up >> ((row - col0) * 8u)) & 0xFFu);
  }
  uint inc = ct;
#pragma unroll
  for (uint off = 1; off < 64u; off <<= 1) {
    const uint nv = __shfl_up(inc, off, 64);
    if (lane >= off) inc += nv;
  }
  const float wacc = wave_sum(acc);
  if (lane == 63u) redc[wid] = inc;
  if (lane == 0u) redf[wid] = wacc;
  __syncthreads();
  uint wbase = 0;
  for (uint w = 0; w < wid; ++w) wbase += redc[w];
  if (t == 0u) {
    nnz[row] = min(redc[0] + redc[1] + redc[2] + redc[3], CAP);
    R[row] = 1.f / (redf[0] + redf[1] + redf[2] + redf[3]);
  }
  uint ofs = wbase + inc - ct;
  const size_t rb = (size_t)row * CAP;
#pragma unroll
  for (uint ch = 0; ch < 8u; ++ch) {
    const uint up = pk[ch];
    const uint col0 = ch * 1024u + t * 4u;
#pragma unroll
    for (uint e = 0; e < 4u; ++e) {
      const uint bb = (up >> (8u * e)) & 0xFFu;
      if (bb) {
        if (ofs < CAP) rent[rb + ofs] = (col0 + e) | (bb << 16);
        ++ofs;
      }
    }
  }
}

__global__ __launch_bounds__(1024) void k_colacc(
    const uint* __restrict__ rent, const uint* __restrict__ nnz,
    const float* __restrict__ R, float* __restrict__ part) {
  __shared__ float Cp[NN];
  const uint t = threadIdx.x;
#pragma unroll
  for (uint j = t; j < NN; j += 1024u) Cp[j] = 0.f;
  __syncthreads();
  const uint lane = t & 63u, w = t >> 6;
  const uint row0 = blockIdx.x * 32u;
#pragma unroll
  for (uint rr = 0; rr < 2u; ++rr) {
    const uint row = row0 + w * 2u + rr;
    const float Rr = R[row];
    const uint n = nnz[row];
    const size_t base = (size_t)row * CAP;
    for (uint k = lane; k < n; k += 64u) {
      const uint e = rent[base + k];
      atomicAdd(&Cp[e & 0xFFFFu], cvt8(e >> 16) * Rr);
    }
  }
  __syncthreads();
  float* po = part + (size_t)blockIdx.x * NN;
#pragma unroll
  for (uint j4 = t * 4u; j4 < NN; j4 += 4096u)
    *(f32x4*)(po + j4) = *(const f32x4*)(Cp + j4);
}

__global__ __launch_bounds__(1024) void k_colred(
    const float* __restrict__ part, float* __restrict__ C, int fin,
    const float* __restrict__ R, const float* __restrict__ qdiag,
    float* __restrict__ dvec, float* __restrict__ out) {
  __shared__ float red2[3][256];
  __shared__ float red[16];
  const uint t = threadIdx.x;
  const uint lj = t & 255u;
  const uint q = t >> 8;
  const uint j = blockIdx.x * 256u + lj;
  float s = 0.f;
  const uint r0 = q * 64u;
#pragma unroll 8
  for (uint r = r0; r < r0 + 64u; ++r) s += part[(size_t)r * NN + j];
  if (q) red2[q - 1][lj] = s;
  __syncthreads();
  float term = 0.f;
  if (q == 0) {
    s += red2[0][lj] + red2[1][lj] + red2[2][lj];
    const float c = 1.f / s;
    C[j] = c;
    if (fin) {
      const float qd = qdiag[j];
      const float d = qd * R[j] * c;
      dvec[j] = d;
      term = fmaxf(MARGIN - d, 0.f) * (16382.f + (qd != 0.f ? 2.f : 0.f));
    }
  }
  if (fin) {
    term = wave_sum(term);
    if ((t & 63u) == 0u) red[t >> 6] = term;
    __syncthreads();
    if (t == 0u) {
      float tt = 0.f;
#pragma unroll
      for (int w = 0; w < 16; ++w) tt += red[w];
      atomicAdd(out, tt);
    }
  }
}

__global__ __launch_bounds__(256) void k_rowstep(
    const uint* __restrict__ rent, const uint* __restrict__ nnz,
    const float* __restrict__ C, float* __restrict__ R) {
  const uint t = threadIdx.x, lane = t & 63u, w = t >> 6;
  const uint row = blockIdx.x * 4u + w;
  const uint n = nnz[row];
  const size_t base = (size_t)row * CAP;
  float acc = 0.f;
  for (uint k = lane; k < n; k += 64u) {
    const uint e = rent[base + k];
    acc += cvt8(e >> 16) * C[e & 0xFFFFu];
  }
  acc = wave_sum(acc);
  if (lane == 0u) R[row] = 1.f / acc;
}

__global__ __launch_bounds__(256) void k_losss(
    const uint* __restrict__ rent, const uint* __restrict__ nnz,
    const float* __restrict__ R, const float* __restrict__ C,
    const float* __restrict__ dvec, float* __restrict__ out) {
  __shared__ float red[4];
  const uint t = threadIdx.x, lane = t & 63u, w = t >> 6;
  const uint row = blockIdx.x * 4u + w;
  const uint n = nnz[row];
  const float Rr = R[row];
  const float dr = dvec[row];
  const size_t base = (size_t)row * CAP;
  float acc = 0.f;
  for (uint k = lane; k < n; k += 64u) {
    const uint e = rent[base + k];
    const uint j = e & 0xFFFFu;
    const float dj = dvec[j];
    acc -= fmaxf(MARGIN - dj, 0.f);
    if (j != row) {
      const float P = cvt8(e >> 16) * Rr * C[j];
      acc += fmaxf(P - dj + MARGIN, 0.f) + fmaxf(P - dr + MARGIN, 0.f);
    }
  }
  if (lane == 0u) acc -= (float)n * fmaxf(MARGIN - dr, 0.f);
  acc = wave_sum(acc);
  if (lane == 0u) red[w] = acc;
  __syncthreads();
  if (t == 0u) atomicAdd(out, red[0] + red[1] + red[2] + red[3]);
}

static void run_sparse(const float* sims, float* out, void* ws,
                       hipStream_t stream) {
  uint* rent = (uint*)ws;
  float* part = (float*)(rent + (size_t)NN * CAP);
  float* R = part + 256u * (size_t)NN;
  float* C = R + NN;
  float* dv = C + NN;
  float* qd = dv + NN;
  uint* nz = (uint*)(qd + NN);
  k_pass0s<<<8192, 256, 0, stream>>>(sims, rent, nz, R, qd, out);
  for (int it = 0; it < 5; ++it) {
    k_colacc<<<256, 1024, 0, stream>>>(rent, nz, R, part);
    k_colred<<<32, 1024, 0, stream>>>(part, C, (it == 4) ? 1 : 0, R, qd, dv,
                                      out);
    if (it < 4) k_rowstep<<<2048, 256, 0, stream>>>(rent, nz, C, R);
  }
  k_losss<<<2048, 256, 0, stream>>>(rent, nz, R, C, dv, out);
}

// =============== FALLBACK 2: dense recompute-from-sims path ==================

__global__ __launch_bounds__(256) void k_pass0d(const float* __restrict__ sims,
                                                float* __restrict__ R) {
  __shared__ float red[4];
  const uint row = blockIdx.x;
  const uint t = threadIdx.x;
  float acc = 0.f;
#pragma unroll
  for (uint ch = 0; ch < 8; ++ch) {
    const uint col = ch * 1024u + t * 4u;
    const float4 s = *(const float4*)(sims + (size_t)row * NN + col);
    acc += exp2f((s.x - 1.f) * KF) + exp2f((s.y - 1.f) * KF) +
           exp2f((s.z - 1.f) * KF) + exp2f((s.w - 1.f) * KF);
  }
  float v = wave_sum(acc);
  const int lane = threadIdx.x & 63, wid = threadIdx.x >> 6;
  if (lane == 0) red[wid] = v;
  __syncthreads();
  if (t == 0) R[row] = 1.f / (red[0] + red[1] + red[2] + red[3]);
}

__global__ __launch_bounds__(256) void k_colmvd(const float* __restrict__ sims,
                                                const float* __restrict__ R,
                                                float* __restrict__ part) {
  const uint t = threadIdx.x;
  const uint col = blockIdx.x * 1024u + t * 4u;
  const uint row0 = blockIdx.y * 64u;
  float a0 = 0.f, a1 = 0.f, a2 = 0.f, a3 = 0.f;
#pragma unroll 8
  for (uint rr = 0; rr < 64u; ++rr) {
    const uint row = row0 + rr;
    const float Rr = R[row];
    const float4 s = *(const float4*)(sims + (size_t)row * NN + col);
    a0 += exp2f((s.x - 1.f) * KF) * Rr;
    a1 += exp2f((s.y - 1.f) * KF) * Rr;
    a2 += exp2f((s.z - 1.f) * KF) * Rr;
    a3 += exp2f((s.w - 1.f) * KF) * Rr;
  }
  float4 o; o.x = a0; o.y = a1; o.z = a2; o.w = a3;
  *(float4*)(part + (size_t)blockIdx.y * NN + col) = o;
}

__global__ __launch_bounds__(1024) void k_colredd(
    const float* __restrict__ part, float* __restrict__ Cg, int fin,
    const float* __restrict__ sims, const float* __restrict__ R,
    float* __restrict__ dvec, float* __restrict__ out) {
  __shared__ float red2[3][256];
  const uint t = threadIdx.x;
  const uint lj = t & 255u;
  const uint q = t >> 8;
  const uint j = blockIdx.x * 256u + lj;
  float s = 0.f;
  const uint r0 = q * 32u;
#pragma unroll 8
  for (uint r = r0; r < r0 + 32u; ++r) s += part[(size_t)r * NN + j];
  if (q) red2[q - 1][lj] = s;
  __syncthreads();
  if (q == 0) {
    s += red2[0][lj] + red2[1][lj] + red2[2][lj];
    const float c = 1.f / s;
    Cg[j] = c;
    if (fin) {
      dvec[j] = exp2f((sims[(size_t)j * 8193u] - 1.f) * KF) * R[j] * c;
      if (j == 0) *out = 0.f;
    }
  }
}

__global__ __launch_bounds__(256) void k_rowmvd(const float* __restrict__ sims,
                                                const float* __restrict__ Cg,
                                                float* __restrict__ R) {
  __shared__ float red[4][4];
  const uint t = threadIdx.x;
  const uint row0 = blockIdx.x * 4u;
  float a0 = 0.f, a1 = 0.f, a2 = 0.f, a3 = 0.f;
#pragma unroll
  for (uint it = 0; it < 8u; ++it) {
    const uint col = it * 1024u + t * 4u;
    const float4 c = *(const float4*)(Cg + col);
    const float* sp = sims + (size_t)row0 * NN + col;
    const float4 s0 = *(const float4*)(sp);
    const float4 s1 = *(const float4*)(sp + NN);
    const float4 s2 = *(const float4*)(sp + 2u * NN);
    const float4 s3 = *(const float4*)(sp + 3u * NN);
    a0 += exp2f((s0.x - 1.f) * KF) * c.x + exp2f((s0.y - 1.f) * KF) * c.y +
          exp2f((s0.z - 1.f) * KF) * c.z + exp2f((s0.w - 1.f) * KF) * c.w;
    a1 += exp2f((s1.x - 1.f) * KF) * c.x + exp2f((s1.y - 1.f) * KF) * c.y +
          exp2f((s1.z - 1.f) * KF) * c.z + exp2f((s1.w - 1.f) * KF) * c.w;
    a2 += exp2f((s2.x - 1.f) * KF) * c.x + exp2f((s2.y - 1.f) * KF) * c.y +
          exp2f((s2.z - 1.f) * KF) * c.z + exp2f((s2.w - 1.f) * KF) * c.w;
    a3 += exp2f((s3.x - 1.f) * KF) * c.x + exp2f((s3.y - 1.f) * KF) * c.y +
          exp2f((s3.z - 1.f) * KF) * c.z + exp2f((s3.w - 1.f) * KF) * c.w;
  }
#pragma unroll
  for (int off = 32; off; off >>= 1) {
    a0 += __shfl_down(a0, off, 64);
    a1 += __shfl_down(a1, off, 64);
    a2 += __shfl_down(a2, off, 64);
    a3 += __shfl_down(a3, off, 64);
  }
  const uint lane = t & 63u, wid = t >> 6;
  if (lane == 0) {
    red[wid][0] = a0; red[wid][1] = a1; red[wid][2] = a2; red[wid][3] = a3;
  }
  __syncthreads();
  if (t < 4u)
    R[row0 + t] = 1.f / (red[0][t] + red[1][t] + red[2][t] + red[3][t]);
}

__global__ __launch_bounds__(256) void k_lossd(const float* __restrict__ sims,
                                               const float* __restrict__ R,
                                               const float* __restrict__ Cg,
                                               const float* __restrict__ dvec,
                                               float* __restrict__ out) {
  __shared__ float red[4];
  const uint t = threadIdx.x;
  const uint col = blockIdx.x * 1024u + t * 4u;
  const uint row0 = blockIdx.y * 128u;
  const float4 c4 = *(const float4*)(Cg + col);
  const float4 d4 = *(const float4*)(dvec + col);
  float acc = 0.f;
#pragma unroll 4
  for (uint rr = 0; rr < 128u; ++rr) {
    const uint row = row0 + rr;
    const float Rr = R[row];
    const float dr = dvec[row];
    const float4 s = *(const float4*)(sims + (size_t)row * NN + col);
    const float f0 = exp2f((s.x - 1.f) * KF);
    const float f1 = exp2f((s.y - 1.f) * KF);
    const float f2 = exp2f((s.z - 1.f) * KF);
    const float f3 = exp2f((s.w - 1.f) * KF);
    float p, h;
    p = f0 * Rr * c4.x;
    h = fmaxf(p - d4.x + MARGIN, 0.f) + fmaxf(p - dr + MARGIN, 0.f);
    acc += (row == col + 0u) ? 0.f : h;
    p = f1 * Rr * c4.y;
    h = fmaxf(p - d4.y + MARGIN, 0.f) + fmaxf(p - dr + MARGIN, 0.f);
    acc += (row == col + 1u) ? 0.f : h;
    p = f2 * Rr * c4.z;
    h = fmaxf(p - d4.z + MARGIN, 0.f) + fmaxf(p - dr + MARGIN, 0.f);
    acc += (row == col + 2u) ? 0.f : h;
    p = f3 * Rr * c4.w;
    h = fmaxf(p - d4.w + MARGIN, 0.f) + fmaxf(p - dr + MARGIN, 0.f);
    acc += (row == col + 3u) ? 0.f : h;
  }
  float v = wave_sum(acc);
  const int lane = threadIdx.x & 63, wid = threadIdx.x >> 6;
  if (lane == 0) red[wid] = v;
  __syncthreads();
  if (t == 0) atomicAdd(out, red[0] + red[1] + red[2] + red[3]);
}

static void run_dense(const float* sims, float* out, void* ws,
                      hipStream_t stream) {
  float* R = (float*)ws;
  float* C = R + NN;
  float* dv = C + NN;
  float* part = dv + NN;  // [128][NN]
  k_pass0d<<<8192, 256, 0, stream>>>(sims, R);
  for (int it = 0; it < 5; ++it) {
    k_colmvd<<<dim3(8, 128), 256, 0, stream>>>(sims, R, part);
    k_colredd<<<32, 1024, 0, stream>>>(part, C, (it == 4) ? 1 : 0, sims, R, dv,
                                       out);
    if (it < 4) k_rowmvd<<<2048, 256, 0, stream>>>(sims, C, R);
  }
  k_lossd<<<dim3(8, 64), 256, 0, stream>>>(sims, R, C, dv, out);
}

// ================================ dispatch ===================================

extern "C" void kernel_launch(void* const* d_in, const int* in_sizes, int n_in,
                              void* d_out, int out_size, void* d_ws,
                              size_t ws_size, hipStream_t stream) {
  const float* sims = (const float*)d_in[0];
  float* out = (float*)d_out;
  const size_t need_sparse = (size_t)NN * CAP * sizeof(uint) +
                             (256u + 4u) * (size_t)NN * sizeof(float) +
                             (size_t)NN * sizeof(uint);
  if (ws_size >= need_sparse) {
    uint* rent = (uint*)d_ws;
    float* part = (float*)(rent + (size_t)NN * CAP);
    float* R = part + 256u * (size_t)NN;
    float* C = R + NN;
    float* dv = C + NN;
    float* qd = dv + NN;
    uint* nz = (uint*)(qd + NN);
    void* args[] = {(void*)&sims, (void*)&rent, (void*)&nz,
                    (void*)&R,    (void*)&C,    (void*)&qd,
                    (void*)&dv,   (void*)&part, (void*)&out};
    const hipError_t e = hipLaunchCooperativeKernel(
        k_coop, dim3(256), dim3(1024), args, 0, stream);
    if (e == hipSuccess) return;
    (void)hipGetLastError();  // clear; fall back to multi-kernel path
    run_sparse(sims, out, d_ws, stream);
  } else {
    run_dense(sims, out, d_ws, stream);  // recompute from sims (slow, safe)
  }
}

// Round 6
// 530.978 us; speedup vs baseline: 1.7437x; 1.7437x over previous
//
#include <hip/hip_runtime.h>

// HubnormTripletLoss, N=8192.
// P = Sinkhorn(exp(-(1-s)/lamb), 5 iters) == P0 * R[i] * C[j]  (diagonal scaling).
// Dense fp8-e4m3 Q (64MB), L3-resident after pass0 (sims NT-read, 256MB dies).
// R5 post-mortem: coop grid-sync = ~stall (640us @ 5% BW) -> back to multi-kernel.
// R1 accounting: harness poison-fill ~160us is INSIDE dur; launch residue ~7us/disp.
// R6: fuse row step into col step (one Q pass per iter, 7->5 passes) and cut
// 16->12 dispatches:
//   pass0: quantize sims -> Q, R1 = 1/rowsum(Q), qdiag, out=0   (8192x256)
//   iter k (x5): k_fused (512 blk x 1024 thr, 16 rows/blk):
//       itx>0: wave w: R[row] = 1/(Q_row . C)  (uint4 Q + float4 C, coalesced)
//       all:   col partials: thread t owns cols 8t..8t+8, reg acc, no atomics
//   k_colred (32x1024): C = 1/sum_512 part; fin: dvec = qdiag*R*C
//   k_loss (8x64 x256): dense hinge over all pairs, skip i==j  (R1-proven)

#define NN 8192u
#define MARGIN 0.2f
#define KF (1.4426950408889634f / 0.012f)  // log2(e)/lamb

typedef float f32x4 __attribute__((ext_vector_type(4)));

__device__ __forceinline__ float wave_sum(float v) {
#pragma unroll
  for (int off = 32; off; off >>= 1) v += __shfl_down(v, off, 64);
  return v;
}

// ============================ FAST DENSE-FP8 PATH ============================

// ---- pass0: quantize -> dense Q, R = 1/rowsum(quantized), qdiag, out=0 ------
__global__ __launch_bounds__(256) void k_pass0(const float* __restrict__ sims,
                                               uint* __restrict__ Qd,
                                               float* __restrict__ R,
                                               float* __restrict__ qdiag,
                                               float* __restrict__ out) {
  __shared__ float red[4];
  const uint row = blockIdx.x, t = threadIdx.x;
  const uint lane = t & 63u, wid = t >> 6;
  if (row == 0u && t == 0u) *out = 0.f;  // d_out poisoned 0xAA each call
  float acc = 0.f;
#pragma unroll
  for (uint ch = 0; ch < 8u; ++ch) {
    const uint col0 = ch * 1024u + t * 4u;
    // nontemporal: sims read exactly once; keep Q resident in L3 instead
    const f32x4 s = __builtin_nontemporal_load(
        (const f32x4*)(sims + (size_t)row * NN + col0));
    int p = 0;
    p = __builtin_amdgcn_cvt_pk_fp8_f32(exp2f((s[0] - 1.f) * KF),
                                        exp2f((s[1] - 1.f) * KF), p, false);
    p = __builtin_amdgcn_cvt_pk_fp8_f32(exp2f((s[2] - 1.f) * KF),
                                        exp2f((s[3] - 1.f) * KF), p, true);
    const uint up = (uint)p;
    Qd[((size_t)row * NN + col0) >> 2] = up;
    auto lo = __builtin_amdgcn_cvt_pk_f32_fp8(p, false);
    auto hi = __builtin_amdgcn_cvt_pk_f32_fp8(p, true);
    acc += (lo[0] + lo[1]) + (hi[0] + hi[1]);  // sum QUANTIZED values
    if (row - col0 < 4u)  // this thread's quad holds the diagonal
      qdiag[row] = __builtin_amdgcn_cvt_f32_fp8(
          (int)((up >> ((row - col0) * 8u)) & 0xFFu), 0);
  }
  const float wacc = wave_sum(acc);
  if (lane == 0u) red[wid] = wacc;
  __syncthreads();
  if (t == 0u) R[row] = 1.f / (red[0] + red[1] + red[2] + red[3]);
}

// ---- fused iteration: [row step if itx>0] + col partials --------------------
// 512 blocks x 1024 threads, 16 rows/block. part[512][NN].
__global__ __launch_bounds__(1024, 4) void k_fused(const uint* __restrict__ Qd,
                                                   float* __restrict__ Rg,
                                                   const float* __restrict__ Cg,
                                                   float* __restrict__ part,
                                                   int itx) {
  __shared__ float Rl[16];
  const uint b = blockIdx.x, t = threadIdx.x;
  const uint lane = t & 63u, w = t >> 6;  // 16 waves, 1 row each
  const uint row0 = b * 16u;
  if (itx == 0) {
    if (t < 16u) Rl[t] = Rg[row0 + t];
  } else {
    // row step: R[row] = 1/(Q_row . C); Q uint4 (16 fp8), C float4 — coalesced
    const uint row = row0 + w;
    const uint* qr = Qd + (size_t)row * 2048u;
    float a = 0.f;
#pragma unroll 2
    for (uint m = 0; m < 8u; ++m) {
      const uint dw = m * 256u + lane * 4u;
      const uint4 q = *(const uint4*)(qr + dw);
      const float4* cp = (const float4*)(Cg + dw * 4u);
      const float4 c0 = cp[0], c1 = cp[1], c2 = cp[2], c3 = cp[3];
      auto l0 = __builtin_amdgcn_cvt_pk_f32_fp8((int)q.x, false);
      auto h0 = __builtin_amdgcn_cvt_pk_f32_fp8((int)q.x, true);
      a += l0[0] * c0.x + l0[1] * c0.y + h0[0] * c0.z + h0[1] * c0.w;
      auto l1 = __builtin_amdgcn_cvt_pk_f32_fp8((int)q.y, false);
      auto h1 = __builtin_amdgcn_cvt_pk_f32_fp8((int)q.y, true);
      a += l1[0] * c1.x + l1[1] * c1.y + h1[0] * c1.z + h1[1] * c1.w;
      auto l2 = __builtin_amdgcn_cvt_pk_f32_fp8((int)q.z, false);
      auto h2 = __builtin_amdgcn_cvt_pk_f32_fp8((int)q.z, true);
      a += l2[0] * c2.x + l2[1] * c2.y + h2[0] * c2.z + h2[1] * c2.w;
      auto l3 = __builtin_amdgcn_cvt_pk_f32_fp8((int)q.w, false);
      auto h3 = __builtin_amdgcn_cvt_pk_f32_fp8((int)q.w, true);
      a += l3[0] * c3.x + l3[1] * c3.y + h3[0] * c3.z + h3[1] * c3.w;
    }
    a = wave_sum(a);
    if (lane == 0u) {
      const float r = 1.f / a;
      Rg[row] = r;
      Rl[w] = r;
    }
  }
  __syncthreads();
  // col partials: thread t owns cols 8t..8t+8 (uint2 = 8 fp8/row, coalesced)
  float a0 = 0.f, a1 = 0.f, a2 = 0.f, a3 = 0.f;
  float a4 = 0.f, a5 = 0.f, a6 = 0.f, a7 = 0.f;
  const uint cd = t * 2u;
#pragma unroll 4
  for (uint r = 0; r < 16u; ++r) {
    const float Rr = Rl[r];
    const uint2 q = *(const uint2*)(Qd + (size_t)(row0 + r) * 2048u + cd);
    auto lo = __builtin_amdgcn_cvt_pk_f32_fp8((int)q.x, false);
    auto hi = __builtin_amdgcn_cvt_pk_f32_fp8((int)q.x, true);
    a0 += lo[0] * Rr; a1 += lo[1] * Rr; a2 += hi[0] * Rr; a3 += hi[1] * Rr;
    lo = __builtin_amdgcn_cvt_pk_f32_fp8((int)q.y, false);
    hi = __builtin_amdgcn_cvt_pk_f32_fp8((int)q.y, true);
    a4 += lo[0] * Rr; a5 += lo[1] * Rr; a6 += hi[0] * Rr; a7 += hi[1] * Rr;
  }
  float* po = part + (size_t)b * NN + t * 8u;
  float4 o;
  o.x = a0; o.y = a1; o.z = a2; o.w = a3;
  *(float4*)(po) = o;
  o.x = a4; o.y = a5; o.z = a6; o.w = a7;
  *(float4*)(po + 4) = o;
}

// ---- col reduce: C[j]=1/sum_512 part[b][j]; fin: dvec -----------------------
__global__ __launch_bounds__(1024) void k_colred(const float* __restrict__ part,
                                                 float* __restrict__ C, int fin,
                                                 const float* __restrict__ R,
                                                 const float* __restrict__ qdiag,
                                                 float* __restrict__ dvec) {
  __shared__ float red2[3][256];
  const uint t = threadIdx.x;
  const uint lj = t & 255u;
  const uint q = t >> 8;  // 0..3: which 128-partial slice
  const uint j = blockIdx.x * 256u + lj;
  float s = 0.f;
  const uint r0 = q * 128u;
#pragma unroll 8
  for (uint r = r0; r < r0 + 128u; ++r) s += part[(size_t)r * NN + j];
  if (q) red2[q - 1][lj] = s;
  __syncthreads();
  if (q == 0) {
    s += red2[0][lj] + red2[1][lj] + red2[2][lj];
    const float c = 1.f / s;
    C[j] = c;
    if (fin) dvec[j] = qdiag[j] * R[j] * c;
  }
}

// ---- loss: sum_{i!=j} max(P-d[j]+m,0)+max(P-d[i]+m,0), P=Q*R[i]*C[j] --------
__global__ __launch_bounds__(256) void k_loss(const uint* __restrict__ Qd,
                                              const float* __restrict__ R,
                                              const float* __restrict__ Cg,
                                              const float* __restrict__ dvec,
                                              float* __restrict__ out) {
  __shared__ float red[4];
  const uint t = threadIdx.x;
  const uint col = blockIdx.x * 1024u + t * 4u;
  const uint row0 = blockIdx.y * 128u;
  const float4 c4 = *(const float4*)(Cg + col);
  const float4 d4 = *(const float4*)(dvec + col);
  float acc = 0.f;
#pragma unroll 4
  for (uint rr = 0; rr < 128u; ++rr) {
    const uint row = row0 + rr;
    const float Rr = R[row];      // uniform -> scalar
    const float dr = dvec[row];   // uniform -> scalar
    const uint q = Qd[((size_t)row * NN + col) >> 2];
    auto lo = __builtin_amdgcn_cvt_pk_f32_fp8((int)q, false);
    auto hi = __builtin_amdgcn_cvt_pk_f32_fp8((int)q, true);
    float p, h;
    p = lo[0] * Rr * c4.x;
    h = fmaxf(p - d4.x + MARGIN, 0.f) + fmaxf(p - dr + MARGIN, 0.f);
    acc += (row == col + 0u) ? 0.f : h;
    p = lo[1] * Rr * c4.y;
    h = fmaxf(p - d4.y + MARGIN, 0.f) + fmaxf(p - dr + MARGIN, 0.f);
    acc += (row == col + 1u) ? 0.f : h;
    p = hi[0] * Rr * c4.z;
    h = fmaxf(p - d4.z + MARGIN, 0.f) + fmaxf(p - dr + MARGIN, 0.f);
    acc += (row == col + 2u) ? 0.f : h;
    p = hi[1] * Rr * c4.w;
    h = fmaxf(p - d4.w + MARGIN, 0.f) + fmaxf(p - dr + MARGIN, 0.f);
    acc += (row == col + 3u) ? 0.f : h;
  }
  const float v = wave_sum(acc);
  const uint lane = t & 63u, wid = t >> 6;
  if (lane == 0u) red[wid] = v;
  __syncthreads();
  if (t == 0u) atomicAdd(out, red[0] + red[1] + red[2] + red[3]);
}

static void run_fast(const float* sims, float* out, void* ws,
                     hipStream_t stream) {
  uint* Qd = (uint*)ws;                                // 64 MB dense fp8
  float* part = (float*)(Qd + (size_t)NN * NN / 4u);   // 16 MB [512][NN]
  float* R = part + 512u * (size_t)NN;
  float* C = R + NN;
  float* dv = C + NN;
  float* qd = dv + NN;

  k_pass0<<<8192, 256, 0, stream>>>(sims, Qd, R, qd, out);
  for (int it = 0; it < 5; ++it) {
    k_fused<<<512, 1024, 0, stream>>>(Qd, R, C, part, it);
    k_colred<<<32, 1024, 0, stream>>>(part, C, (it == 4) ? 1 : 0, R, qd, dv);
  }
  k_loss<<<dim3(8, 64), 256, 0, stream>>>(Qd, R, C, dv, out);
}

// =============== FALLBACK: dense recompute-from-sims path ====================

__global__ __launch_bounds__(256) void k_pass0d(const float* __restrict__ sims,
                                                float* __restrict__ R) {
  __shared__ float red[4];
  const uint row = blockIdx.x;
  const uint t = threadIdx.x;
  float acc = 0.f;
#pragma unroll
  for (uint ch = 0; ch < 8; ++ch) {
    const uint col = ch * 1024u + t * 4u;
    const float4 s = *(const float4*)(sims + (size_t)row * NN + col);
    acc += exp2f((s.x - 1.f) * KF) + exp2f((s.y - 1.f) * KF) +
           exp2f((s.z - 1.f) * KF) + exp2f((s.w - 1.f) * KF);
  }
  float v = wave_sum(acc);
  const int lane = threadIdx.x & 63, wid = threadIdx.x >> 6;
  if (lane == 0) red[wid] = v;
  __syncthreads();
  if (t == 0) R[row] = 1.f / (red[0] + red[1] + red[2] + red[3]);
}

__global__ __launch_bounds__(256) void k_colmvd(const float* __restrict__ sims,
                                                const float* __restrict__ R,
                                                float* __restrict__ part) {
  const uint t = threadIdx.x;
  const uint col = blockIdx.x * 1024u + t * 4u;
  const uint row0 = blockIdx.y * 64u;
  float a0 = 0.f, a1 = 0.f, a2 = 0.f, a3 = 0.f;
#pragma unroll 8
  for (uint rr = 0; rr < 64u; ++rr) {
    const uint row = row0 + rr;
    const float Rr = R[row];
    const float4 s = *(const float4*)(sims + (size_t)row * NN + col);
    a0 += exp2f((s.x - 1.f) * KF) * Rr;
    a1 += exp2f((s.y - 1.f) * KF) * Rr;
    a2 += exp2f((s.z - 1.f) * KF) * Rr;
    a3 += exp2f((s.w - 1.f) * KF) * Rr;
  }
  float4 o; o.x = a0; o.y = a1; o.z = a2; o.w = a3;
  *(float4*)(part + (size_t)blockIdx.y * NN + col) = o;
}

__global__ __launch_bounds__(1024) void k_colredd(
    const float* __restrict__ part, float* __restrict__ Cg, int fin,
    const float* __restrict__ sims, const float* __restrict__ R,
    float* __restrict__ dvec, float* __restrict__ out) {
  __shared__ float red2[3][256];
  const uint t = threadIdx.x;
  const uint lj = t & 255u;
  const uint q = t >> 8;
  const uint j = blockIdx.x * 256u + lj;
  float s = 0.f;
  const uint r0 = q * 32u;
#pragma unroll 8
  for (uint r = r0; r < r0 + 32u; ++r) s += part[(size_t)r * NN + j];
  if (q) red2[q - 1][lj] = s;
  __syncthreads();
  if (q == 0) {
    s += red2[0][lj] + red2[1][lj] + red2[2][lj];
    const float c = 1.f / s;
    Cg[j] = c;
    if (fin) {
      dvec[j] = exp2f((sims[(size_t)j * 8193u] - 1.f) * KF) * R[j] * c;
      if (j == 0) *out = 0.f;
    }
  }
}

__global__ __launch_bounds__(256) void k_rowmvd(const float* __restrict__ sims,
                                                const float* __restrict__ Cg,
                                                float* __restrict__ R) {
  __shared__ float red[4][4];
  const uint t = threadIdx.x;
  const uint row0 = blockIdx.x * 4u;
  float a0 = 0.f, a1 = 0.f, a2 = 0.f, a3 = 0.f;
#pragma unroll
  for (uint it = 0; it < 8u; ++it) {
    const uint col = it * 1024u + t * 4u;
    const float4 c = *(const float4*)(Cg + col);
    const float* sp = sims + (size_t)row0 * NN + col;
    const float4 s0 = *(const float4*)(sp);
    const float4 s1 = *(const float4*)(sp + NN);
    const float4 s2 = *(const float4*)(sp + 2u * NN);
    const float4 s3 = *(const float4*)(sp + 3u * NN);
    a0 += exp2f((s0.x - 1.f) * KF) * c.x + exp2f((s0.y - 1.f) * KF) * c.y +
          exp2f((s0.z - 1.f) * KF) * c.z + exp2f((s0.w - 1.f) * KF) * c.w;
    a1 += exp2f((s1.x - 1.f) * KF) * c.x + exp2f((s1.y - 1.f) * KF) * c.y +
          exp2f((s1.z - 1.f) * KF) * c.z + exp2f((s1.w - 1.f) * KF) * c.w;
    a2 += exp2f((s2.x - 1.f) * KF) * c.x + exp2f((s2.y - 1.f) * KF) * c.y +
          exp2f((s2.z - 1.f) * KF) * c.z + exp2f((s2.w - 1.f) * KF) * c.w;
    a3 += exp2f((s3.x - 1.f) * KF) * c.x + exp2f((s3.y - 1.f) * KF) * c.y +
          exp2f((s3.z - 1.f) * KF) * c.z + exp2f((s3.w - 1.f) * KF) * c.w;
  }
#pragma unroll
  for (int off = 32; off; off >>= 1) {
    a0 += __shfl_down(a0, off, 64);
    a1 += __shfl_down(a1, off, 64);
    a2 += __shfl_down(a2, off, 64);
    a3 += __shfl_down(a3, off, 64);
  }
  const uint lane = t & 63u, wid = t >> 6;
  if (lane == 0) {
    red[wid][0] = a0; red[wid][1] = a1; red[wid][2] = a2; red[wid][3] = a3;
  }
  __syncthreads();
  if (t < 4u)
    R[row0 + t] = 1.f / (red[0][t] + red[1][t] + red[2][t] + red[3][t]);
}

__global__ __launch_bounds__(256) void k_lossd(const float* __restrict__ sims,
                                               const float* __restrict__ R,
                                               const float* __restrict__ Cg,
                                               const float* __restrict__ dvec,
                                               float* __restrict__ out) {
  __shared__ float red[4];
  const uint t = threadIdx.x;
  const uint col = blockIdx.x * 1024u + t * 4u;
  const uint row0 = blockIdx.y * 128u;
  const float4 c4 = *(const float4*)(Cg + col);
  const float4 d4 = *(const float4*)(dvec + col);
  float acc = 0.f;
#pragma unroll 4
  for (uint rr = 0; rr < 128u; ++rr) {
    const uint row = row0 + rr;
    const float Rr = R[row];
    const float dr = dvec[row];
    const float4 s = *(const float4*)(sims + (size_t)row * NN + col);
    const float f0 = exp2f((s.x - 1.f) * KF);
    const float f1 = exp2f((s.y - 1.f) * KF);
    const float f2 = exp2f((s.z - 1.f) * KF);
    const float f3 = exp2f((s.w - 1.f) * KF);
    float p, h;
    p = f0 * Rr * c4.x;
    h = fmaxf(p - d4.x + MARGIN, 0.f) + fmaxf(p - dr + MARGIN, 0.f);
    acc += (row == col + 0u) ? 0.f : h;
    p = f1 * Rr * c4.y;
    h = fmaxf(p - d4.y + MARGIN, 0.f) + fmaxf(p - dr + MARGIN, 0.f);
    acc += (row == col + 1u) ? 0.f : h;
    p = f2 * Rr * c4.z;
    h = fmaxf(p - d4.z + MARGIN, 0.f) + fmaxf(p - dr + MARGIN, 0.f);
    acc += (row == col + 2u) ? 0.f : h;
    p = f3 * Rr * c4.w;
    h = fmaxf(p - d4.w + MARGIN, 0.f) + fmaxf(p - dr + MARGIN, 0.f);
    acc += (row == col + 3u) ? 0.f : h;
  }
  float v = wave_sum(acc);
  const int lane = threadIdx.x & 63, wid = threadIdx.x >> 6;
  if (lane == 0) red[wid] = v;
  __syncthreads();
  if (t == 0) atomicAdd(out, red[0] + red[1] + red[2] + red[3]);
}

static void run_dense(const float* sims, float* out, void* ws,
                      hipStream_t stream) {
  float* R = (float*)ws;
  float* C = R + NN;
  float* dv = C + NN;
  float* part = dv + NN;  // [128][NN]
  k_pass0d<<<8192, 256, 0, stream>>>(sims, R);
  for (int it = 0; it < 5; ++it) {
    k_colmvd<<<dim3(8, 128), 256, 0, stream>>>(sims, R, part);
    k_colredd<<<32, 1024, 0, stream>>>(part, C, (it == 4) ? 1 : 0, sims, R, dv,
                                       out);
    if (it < 4) k_rowmvd<<<2048, 256, 0, stream>>>(sims, C, R);
  }
  k_lossd<<<dim3(8, 64), 256, 0, stream>>>(sims, R, C, dv, out);
}

// ================================ dispatch ===================================

extern "C" void kernel_launch(void* const* d_in, const int* in_sizes, int n_in,
                              void* d_out, int out_size, void* d_ws,
                              size_t ws_size, hipStream_t stream) {
  const float* sims = (const float*)d_in[0];
  float* out = (float*)d_out;
  // fast: Qd 64MB + part 16MB + 4 f32 vectors
  const size_t need_fast = (size_t)NN * NN +
                           (512u + 4u) * (size_t)NN * sizeof(float);
  if (ws_size >= need_fast) {
    run_fast(sims, out, d_ws, stream);
  } else {
    run_dense(sims, out, d_ws, stream);  // recompute from sims (slow, safe)
  }
}